// Round 8
// baseline (1775.990 us; speedup 1.0000x reference)
//
#include <hip/hip_runtime.h>

#define N_NODES_C 100000
#define N_EDGES_C 600000
#define HIDDEN_C 128
#define K_HOPS_C 10
#define SCAN_B 98   // ceil(100000/1024)
#define PROP_BLOCKS 1024  // 4 blocks/CU guaranteed co-resident (256 CUs)

typedef short short8 __attribute__((ext_vector_type(8)));   // 8 bf16 (4 VGPRs)
typedef float f32x16 __attribute__((ext_vector_type(16)));  // 32x32 accumulator

// ---- bf16 helpers (round-to-nearest-even pack, exact unpack) ----
__device__ __forceinline__ unsigned short f2bf(float f) {
    unsigned u = __float_as_uint(f);
    return (unsigned short)((u + 0x7FFFu + ((u >> 16) & 1u)) >> 16);
}
__device__ __forceinline__ float bf_lo(unsigned p) { return __uint_as_float(p << 16); }
__device__ __forceinline__ float bf_hi(unsigned p) { return __uint_as_float(p & 0xFFFF0000u); }

// ---------------- degree count + within-dst rank ---------------------------
__global__ void k_deg(const int* __restrict__ dst, int* __restrict__ deg,
                      unsigned short* __restrict__ rank, int E) {
    int e = blockIdx.x * blockDim.x + threadIdx.x;
    if (e < E) {
        int r = atomicAdd(&deg[dst[e]], 1);
        rank[e] = (unsigned short)r;
    }
}

// ---------------- multi-block exclusive scan, phase A ----------------------
__global__ __launch_bounds__(1024) void k_scan_a(const int* __restrict__ deg,
                                                 int* __restrict__ offs,
                                                 int* __restrict__ blksum,
                                                 float* __restrict__ dinv,
                                                 int* __restrict__ deghist, int N) {
    __shared__ int wtot[16];
    __shared__ int lhist[64];
    int tid = threadIdx.x;
    int i = blockIdx.x * 1024 + tid;
    int lane = tid & 63;
    int wid = tid >> 6;
    if (tid < 64) lhist[tid] = 0;
    __syncthreads();
    int v = (i < N) ? deg[i] : 0;
    if (i < N) {
        dinv[i] = rsqrtf((float)(v + 1));
        atomicAdd(&lhist[v < 63 ? v : 63], 1);
    }
    int incl = v;
#pragma unroll
    for (int d = 1; d < 64; d <<= 1) {
        int t = __shfl_up(incl, (unsigned)d, 64);
        if (lane >= d) incl += t;
    }
    if (lane == 63) wtot[wid] = incl;
    __syncthreads();
    int woff = 0, btot = 0;
#pragma unroll
    for (int w = 0; w < 16; ++w) {
        int t = wtot[w];
        if (w < wid) woff += t;
        btot += t;
    }
    if (i < N) offs[i] = woff + incl - v;
    if (tid == 0) blksum[blockIdx.x] = btot;
    if (tid < 64 && lhist[tid] != 0) atomicAdd(&deghist[tid], lhist[tid]);
}

// ---------------- phase B: scan 98 block sums + 64 bucket sums -------------
__global__ __launch_bounds__(128) void k_scan_b(const int* __restrict__ blksum,
                                                int* __restrict__ blkoff,
                                                int* __restrict__ offs,
                                                const int* __restrict__ deghist,
                                                int* __restrict__ bucketcur,
                                                int NB, int N) {
    __shared__ int wt[2];
    int t = threadIdx.x;
    int lane = t & 63;
    int w = t >> 6;
    int v = (t < NB) ? blksum[t] : 0;
    int incl = v;
#pragma unroll
    for (int d = 1; d < 64; d <<= 1) {
        int s = __shfl_up(incl, (unsigned)d, 64);
        if (lane >= d) incl += s;
    }
    if (lane == 63) wt[w] = incl;
    __syncthreads();
    int excl = incl - v + (w == 1 ? wt[0] : 0);
    if (t < NB) blkoff[t] = excl;
    if (t == 127) offs[N] = wt[0] + wt[1];
    if (w == 0) {
        int hv = deghist[lane];
        int hincl = hv;
#pragma unroll
        for (int d = 1; d < 64; d <<= 1) {
            int s = __shfl_up(hincl, (unsigned)d, 64);
            if (lane >= d) hincl += s;
        }
        bucketcur[lane] = hincl - hv;
    }
}

// ---------------- phase C: block offsets, degree-sorted meta + inverse -----
__global__ __launch_bounds__(1024) void k_scan_c(int* __restrict__ offs,
                                                 const int* __restrict__ blkoff,
                                                 const int* __restrict__ deg,
                                                 const float* __restrict__ dinv,
                                                 int* __restrict__ bucketcur,
                                                 uint4* __restrict__ meta,
                                                 int* __restrict__ inv, int N) {
    __shared__ int lcnt[64];
    __shared__ int lbase[64];
    int tid = threadIdx.x;
    int i = blockIdx.x * 1024 + tid;
    if (tid < 64) lcnt[tid] = 0;
    __syncthreads();
    int v = 0, d = 0, b = 0, lpos = 0;
    if (i < N) {
        v = offs[i] + blkoff[blockIdx.x];
        offs[i] = v;
        d = deg[i];
        b = d < 63 ? d : 63;
        lpos = atomicAdd(&lcnt[b], 1);
    }
    __syncthreads();
    if (tid < 64) lbase[tid] = (lcnt[tid] != 0) ? atomicAdd(&bucketcur[tid], lcnt[tid]) : 0;
    __syncthreads();
    if (i < N) {
        int pos = lbase[b] + lpos;
        float dv = dinv[i];
        meta[pos] = make_uint4((unsigned)v, (unsigned)(v + d), (unsigned)i,
                               __float_as_uint(dv * dv));
        inv[i] = pos;
    }
}

// ---------------- CSR fill: store slot-of-src (atomic-free) ----------------
__global__ void k_fill(const int* __restrict__ src, const int* __restrict__ dst,
                       const unsigned short* __restrict__ rank,
                       const float* __restrict__ dinv, const int* __restrict__ offs,
                       const int* __restrict__ inv,
                       uint2* __restrict__ csr, int E) {
    int e = blockIdx.x * blockDim.x + threadIdx.x;
    if (e < E) {
        int s = src[e], d = dst[e];
        int pos = offs[d] + (int)rank[e];
        uint2 v;
        v.x = (unsigned)inv[s];                       // slot id of source
        v.y = __float_as_uint(dinv[s] * dinv[d]);
        csr[pos] = v;
    }
}

// ------- h0b[slot] = bf16(x[node] @ W^T + b) via 32x32x16 bf16 MFMA --------
__global__ __launch_bounds__(256) void k_gemm(const float* __restrict__ x,
                                              const float* __restrict__ W,
                                              const float* __restrict__ b,
                                              const int* __restrict__ inv,
                                              unsigned short* __restrict__ hb, int N) {
    __shared__ unsigned short Wb[HIDDEN_C * HIDDEN_C];  // 32 KiB bf16
    int tid = threadIdx.x;
#pragma unroll
    for (int i = 0; i < 8; ++i) {
        int c = tid + 256 * i;      // 0..2047
        int m = c >> 4;             // W row (output o)
        int g = c & 15;             // 8-element group within row
        const float4* wsrc = (const float4*)W + m * 32 + g * 2;
        float4 wa = wsrc[0];
        float4 wb = wsrc[1];
        unsigned short t8[8];
        t8[0] = f2bf(wa.x); t8[1] = f2bf(wa.y); t8[2] = f2bf(wa.z); t8[3] = f2bf(wa.w);
        t8[4] = f2bf(wb.x); t8[5] = f2bf(wb.y); t8[6] = f2bf(wb.z); t8[7] = f2bf(wb.w);
        int gs = g ^ (m & 15);
        *(uint4*)&Wb[m * 128 + gs * 8] = *(const uint4*)t8;
    }
    __syncthreads();

    int lane = tid & 63;
    int wv = tid >> 6;
    int row0 = blockIdx.x * 128 + wv * 32;
    int m = lane & 31;
    int half = lane >> 5;

    int row = row0 + m;
    if (row >= N) row = N - 1;
    const float4* xrow = (const float4*)(x + (size_t)row * 128);

    f32x16 acc[4];
#pragma unroll
    for (int t = 0; t < 4; ++t)
#pragma unroll
        for (int r = 0; r < 16; ++r) acc[t][r] = 0.f;

    for (int s = 0; s < 8; ++s) {
        int kb = s * 16 + half * 8;
        float4 x0 = xrow[kb >> 2];
        float4 x1 = xrow[(kb >> 2) + 1];
        union { unsigned short u[8]; short8 v; } af;
        af.u[0] = f2bf(x0.x); af.u[1] = f2bf(x0.y); af.u[2] = f2bf(x0.z); af.u[3] = f2bf(x0.w);
        af.u[4] = f2bf(x1.x); af.u[5] = f2bf(x1.y); af.u[6] = f2bf(x1.z); af.u[7] = f2bf(x1.w);
        int g = kb >> 3;
#pragma unroll
        for (int t = 0; t < 4; ++t) {
            int r = t * 32 + m;
            short8 bfrag = *(const short8*)&Wb[r * 128 + ((g ^ (r & 15)) << 3)];
            acc[t] = __builtin_amdgcn_mfma_f32_32x32x16_bf16(af.v, bfrag, acc[t], 0, 0, 0);
        }
    }

    float bias[4];
#pragma unroll
    for (int t = 0; t < 4; ++t) bias[t] = b[t * 32 + m];
#pragma unroll
    for (int t = 0; t < 4; ++t) {
#pragma unroll
        for (int r = 0; r < 16; ++r) {
            int rrow = (r & 3) + 8 * (r >> 2) + 4 * half;
            int node = row0 + rrow;
            if (node < N) {
                int slot = inv[node];
                float v = acc[t][r] + bias[t];
                hb[(size_t)slot * 128 + t * 32 + m] = f2bf(v);
            }
        }
    }
}

// ---- device-scope grid barrier (sense via generation counter) -------------
// bar[0] = arrival counter, bar[1] = generation. AGENT-scope release on
// arrival publishes this block's hop-k writes (L2 writeback); acquire on the
// generation load invalidates stale lines before hop k+1 reads. This is the
// same protocol cooperative grid.sync() uses. All PROP_BLOCKS are co-resident
// (launch_bounds(256,4) => >=4 blocks/CU * 256 CUs >= 1024), so no deadlock.
__device__ __forceinline__ void grid_barrier(int* bar, int nblocks, int gen) {
    __syncthreads();  // compiler drains vmcnt before s_barrier => stores in L2
    if (threadIdx.x == 0) {
        int prev = __hip_atomic_fetch_add(&bar[0], 1, __ATOMIC_ACQ_REL,
                                          __HIP_MEMORY_SCOPE_AGENT);
        if (prev == nblocks - 1) {
            __hip_atomic_store(&bar[0], 0, __ATOMIC_RELAXED, __HIP_MEMORY_SCOPE_AGENT);
            __hip_atomic_store(&bar[1], gen + 1, __ATOMIC_RELEASE,
                               __HIP_MEMORY_SCOPE_AGENT);
        } else {
            while (__hip_atomic_load(&bar[1], __ATOMIC_ACQUIRE,
                                     __HIP_MEMORY_SCOPE_AGENT) <= gen) {
                __builtin_amdgcn_s_sleep(2);
            }
        }
    }
    __syncthreads();
}

// ---- all 10 APPNP hops in one persistent kernel ---------------------------
// v8: per hop, wave = 4 degree-balanced slots; heaviest quads first (sorted
// ascending -> iterate descending) so the per-hop barrier has no fat tail.
// Hops 1..9 write bf16 ping-pong (slot space, streaming); hop 10 scatters
// fp32 to d_out by original node id. Saves 9 dispatch boundaries.
__global__ __launch_bounds__(256, 4) void k_prop10(const uint4* __restrict__ h04,
                                                   uint4* __restrict__ bufA,
                                                   uint4* __restrict__ bufB,
                                                   float* __restrict__ hout_f,
                                                   const uint4* __restrict__ meta,
                                                   const uint2* __restrict__ csr,
                                                   int* __restrict__ bar,
                                                   int N) {
    int tid = threadIdx.x;
    int lane = tid & 63;
    int wid = tid >> 6;
    int q = lane >> 4;   // slot within quad
    int f = lane & 15;   // 16B chunk within row

    int nquads = (N + 3) >> 2;
    int wave_g = blockIdx.x * 4 + wid;
    int nwaves = gridDim.x * 4;

    for (int k = 0; k < K_HOPS_C; ++k) {
        const uint4* hin4 = (k == 0) ? h04 : ((k & 1) ? bufA : bufB);
        uint4* houtb = (k & 1) ? bufB : bufA;
        int fin = (k == K_HOPS_C - 1);

        for (int t = wave_g; t < nquads; t += nwaves) {
            int quad = nquads - 1 - t;           // heaviest first
            int slot = quad * 4 + q;
            bool valid = slot < N;

            int node = 0, beg = 0, end = 0;
            float ws = 0.f;
            if (valid) {
                uint4 m = meta[slot];
                beg = (int)m.x;
                end = (int)m.y;
                node = (int)m.z;
                ws = __uint_as_float(m.w);
            }

            uint4 hq = make_uint4(0u, 0u, 0u, 0u);
            uint4 ps = make_uint4(0u, 0u, 0u, 0u);
            if (valid) {
                hq = h04[(size_t)slot * 16 + f];
                ps = hin4[(size_t)slot * 16 + f];
            }

            float acc[8];
#pragma unroll
            for (int i = 0; i < 8; ++i) acc[i] = 0.f;

#pragma unroll 2
            for (int j = beg; j < end; j += 4) {
                int j1 = (j + 1 < end) ? j + 1 : j;
                int j2 = (j + 2 < end) ? j + 2 : j;
                int j3 = (j + 3 < end) ? j + 3 : j;
                uint2 e0 = csr[j];
                uint2 e1 = csr[j1];
                uint2 e2 = csr[j2];
                uint2 e3 = csr[j3];
                uint4 p0 = hin4[(size_t)e0.x * 16 + f];
                uint4 p1 = hin4[(size_t)e1.x * 16 + f];
                uint4 p2 = hin4[(size_t)e2.x * 16 + f];
                uint4 p3 = hin4[(size_t)e3.x * 16 + f];
                float w0 = __uint_as_float(e0.y);
                float w1 = (j + 1 < end) ? __uint_as_float(e1.y) : 0.f;
                float w2 = (j + 2 < end) ? __uint_as_float(e2.y) : 0.f;
                float w3 = (j + 3 < end) ? __uint_as_float(e3.y) : 0.f;
                acc[0] += w0 * bf_lo(p0.x); acc[1] += w0 * bf_hi(p0.x);
                acc[2] += w0 * bf_lo(p0.y); acc[3] += w0 * bf_hi(p0.y);
                acc[4] += w0 * bf_lo(p0.z); acc[5] += w0 * bf_hi(p0.z);
                acc[6] += w0 * bf_lo(p0.w); acc[7] += w0 * bf_hi(p0.w);
                acc[0] += w1 * bf_lo(p1.x); acc[1] += w1 * bf_hi(p1.x);
                acc[2] += w1 * bf_lo(p1.y); acc[3] += w1 * bf_hi(p1.y);
                acc[4] += w1 * bf_lo(p1.z); acc[5] += w1 * bf_hi(p1.z);
                acc[6] += w1 * bf_lo(p1.w); acc[7] += w1 * bf_hi(p1.w);
                acc[0] += w2 * bf_lo(p2.x); acc[1] += w2 * bf_hi(p2.x);
                acc[2] += w2 * bf_lo(p2.y); acc[3] += w2 * bf_hi(p2.y);
                acc[4] += w2 * bf_lo(p2.z); acc[5] += w2 * bf_hi(p2.z);
                acc[6] += w2 * bf_lo(p2.w); acc[7] += w2 * bf_hi(p2.w);
                acc[0] += w3 * bf_lo(p3.x); acc[1] += w3 * bf_hi(p3.x);
                acc[2] += w3 * bf_lo(p3.y); acc[3] += w3 * bf_hi(p3.y);
                acc[4] += w3 * bf_lo(p3.z); acc[5] += w3 * bf_hi(p3.z);
                acc[6] += w3 * bf_lo(p3.w); acc[7] += w3 * bf_hi(p3.w);
            }

            // self-loop (ws==0 only for invalid tail slots)
            acc[0] += ws * bf_lo(ps.x); acc[1] += ws * bf_hi(ps.x);
            acc[2] += ws * bf_lo(ps.y); acc[3] += ws * bf_hi(ps.y);
            acc[4] += ws * bf_lo(ps.z); acc[5] += ws * bf_hi(ps.z);
            acc[6] += ws * bf_lo(ps.w); acc[7] += ws * bf_hi(ps.w);

            if (valid) {
                float o[8];
                o[0] = 0.9f * acc[0] + 0.1f * bf_lo(hq.x);
                o[1] = 0.9f * acc[1] + 0.1f * bf_hi(hq.x);
                o[2] = 0.9f * acc[2] + 0.1f * bf_lo(hq.y);
                o[3] = 0.9f * acc[3] + 0.1f * bf_hi(hq.y);
                o[4] = 0.9f * acc[4] + 0.1f * bf_lo(hq.z);
                o[5] = 0.9f * acc[5] + 0.1f * bf_hi(hq.z);
                o[6] = 0.9f * acc[6] + 0.1f * bf_lo(hq.w);
                o[7] = 0.9f * acc[7] + 0.1f * bf_hi(hq.w);
                if (fin) {
                    float4* dst0 = (float4*)(hout_f + (size_t)node * 128 + f * 8);
                    float4 v0; v0.x = o[0]; v0.y = o[1]; v0.z = o[2]; v0.w = o[3];
                    float4 v1; v1.x = o[4]; v1.y = o[5]; v1.z = o[6]; v1.w = o[7];
                    dst0[0] = v0;
                    dst0[1] = v1;
                } else {
                    uint4 p;
                    p.x = (unsigned)f2bf(o[0]) | ((unsigned)f2bf(o[1]) << 16);
                    p.y = (unsigned)f2bf(o[2]) | ((unsigned)f2bf(o[3]) << 16);
                    p.z = (unsigned)f2bf(o[4]) | ((unsigned)f2bf(o[5]) << 16);
                    p.w = (unsigned)f2bf(o[6]) | ((unsigned)f2bf(o[7]) << 16);
                    houtb[(size_t)slot * 16 + f] = p;   // streaming store
                }
            }
        }

        if (!fin) grid_barrier(bar, gridDim.x, k);
    }
}

extern "C" void kernel_launch(void* const* d_in, const int* in_sizes, int n_in,
                              void* d_out, int out_size, void* d_ws, size_t ws_size,
                              hipStream_t stream) {
    const float* x = (const float*)d_in[0];
    const int* edge = (const int*)d_in[1];  // [2, E]: [0]=src, [1]=dst
    const float* W = (const float*)d_in[2];
    const float* b = (const float*)d_in[3];
    float* out = (float*)d_out;

    const int N = N_NODES_C;
    const int E = N_EDGES_C;
    const int* src = edge;
    const int* dst = edge + E;

    char* ws = (char*)d_ws;
    size_t off = 0;
    auto carve = [&](size_t bytes) -> void* {
        void* p = ws + off;
        off = (off + bytes + 511) & ~(size_t)511;
        return p;
    };
    unsigned short* h0b = (unsigned short*)carve((size_t)N * HIDDEN_C * 2);  // 25.6 MB
    unsigned short* bA  = (unsigned short*)carve((size_t)N * HIDDEN_C * 2);  // 25.6 MB
    unsigned short* bB  = (unsigned short*)carve((size_t)N * HIDDEN_C * 2);  // 25.6 MB
    int*   deg     = (int*)  carve(((size_t)N + 80) * sizeof(int));  // deg+hist+bar
    int*   deghist = deg + N;
    int*   bar     = deg + N + 64;       // 2 ints, zeroed by the same memset
    float* dinv    = (float*)carve((size_t)N * sizeof(float));
    int*   offs    = (int*)  carve((size_t)(N + 1) * sizeof(int));
    unsigned short* rank = (unsigned short*)carve((size_t)E * sizeof(unsigned short));
    uint2* csr     = (uint2*)carve((size_t)E * sizeof(uint2));
    int*   blksum  = (int*)  carve((size_t)SCAN_B * sizeof(int));
    int*   blkoff  = (int*)  carve((size_t)SCAN_B * sizeof(int));
    int*   bucketcur = (int*)carve(64 * sizeof(int));
    uint4* meta    = (uint4*)carve((size_t)N * sizeof(uint4));
    int*   inv     = (int*)  carve((size_t)N * sizeof(int));
    (void)ws_size;

    hipMemsetAsync(deg, 0, ((size_t)N + 80) * sizeof(int), stream);

    int eb = (E + 255) / 256;
    k_deg<<<eb, 256, 0, stream>>>(dst, deg, rank, E);
    k_scan_a<<<SCAN_B, 1024, 0, stream>>>(deg, offs, blksum, dinv, deghist, N);
    k_scan_b<<<1, 128, 0, stream>>>(blksum, blkoff, offs, deghist, bucketcur, SCAN_B, N);
    k_scan_c<<<SCAN_B, 1024, 0, stream>>>(offs, blkoff, deg, dinv, bucketcur, meta, inv, N);
    k_fill<<<eb, 256, 0, stream>>>(src, dst, rank, dinv, offs, inv, csr, E);

    k_gemm<<<(N + 127) / 128, 256, 0, stream>>>(x, W, b, inv, h0b, N);

    // all 10 hops in one persistent dispatch with internal grid barriers
    k_prop10<<<PROP_BLOCKS, 256, 0, stream>>>((const uint4*)h0b, (uint4*)bA,
                                              (uint4*)bB, out, meta, csr, bar, N);
}

// Round 10
// 498.717 us; speedup vs baseline: 3.5611x; 3.5611x over previous
//
#include <hip/hip_runtime.h>

#define N_NODES_C 100000
#define N_EDGES_C 600000
#define HIDDEN_C 128
#define K_HOPS_C 10
#define SCAN_B 98  // ceil(100000/1024)

typedef short short8 __attribute__((ext_vector_type(8)));   // 8 bf16 (4 VGPRs)
typedef float f32x16 __attribute__((ext_vector_type(16)));  // 32x32 accumulator

// ---- bf16 helpers (round-to-nearest-even pack, exact unpack) ----
__device__ __forceinline__ unsigned short f2bf(float f) {
    unsigned u = __float_as_uint(f);
    return (unsigned short)((u + 0x7FFFu + ((u >> 16) & 1u)) >> 16);
}
__device__ __forceinline__ float bf_lo(unsigned p) { return __uint_as_float(p << 16); }
__device__ __forceinline__ float bf_hi(unsigned p) { return __uint_as_float(p & 0xFFFF0000u); }

// ---------------- degree count + within-dst rank ---------------------------
// atomicAdd's return IS the edge's rank within its destination — store it so
// k_fill needs no atomic (kills the 600k-atomic latency chain there).
__global__ void k_deg(const int* __restrict__ dst, int* __restrict__ deg,
                      unsigned short* __restrict__ rank, int E) {
    int e = blockIdx.x * blockDim.x + threadIdx.x;
    if (e < E) {
        int r = atomicAdd(&deg[dst[e]], 1);
        rank[e] = (unsigned short)r;
    }
}

// ---------------- multi-block exclusive scan, phase A ----------------------
// also: degree histogram (64 clamp buckets), block-aggregated in LDS first
// (Guideline 12: direct global atomics on ~15 hot addresses cost 365 us in r3)
__global__ __launch_bounds__(1024) void k_scan_a(const int* __restrict__ deg,
                                                 int* __restrict__ offs,
                                                 int* __restrict__ blksum,
                                                 float* __restrict__ dinv,
                                                 int* __restrict__ deghist, int N) {
    __shared__ int wtot[16];
    __shared__ int lhist[64];
    int tid = threadIdx.x;
    int i = blockIdx.x * 1024 + tid;
    int lane = tid & 63;
    int wid = tid >> 6;
    if (tid < 64) lhist[tid] = 0;
    __syncthreads();
    int v = (i < N) ? deg[i] : 0;
    if (i < N) {
        dinv[i] = rsqrtf((float)(v + 1));
        atomicAdd(&lhist[v < 63 ? v : 63], 1);
    }
    int incl = v;
#pragma unroll
    for (int d = 1; d < 64; d <<= 1) {
        int t = __shfl_up(incl, (unsigned)d, 64);
        if (lane >= d) incl += t;
    }
    if (lane == 63) wtot[wid] = incl;
    __syncthreads();
    int woff = 0, btot = 0;
#pragma unroll
    for (int w = 0; w < 16; ++w) {
        int t = wtot[w];
        if (w < wid) woff += t;
        btot += t;
    }
    if (i < N) offs[i] = woff + incl - v;
    if (tid == 0) blksum[blockIdx.x] = btot;
    if (tid < 64 && lhist[tid] != 0) atomicAdd(&deghist[tid], lhist[tid]);
}

// ---------------- phase B: scan 98 block sums + 64 bucket sums -------------
__global__ __launch_bounds__(128) void k_scan_b(const int* __restrict__ blksum,
                                                int* __restrict__ blkoff,
                                                int* __restrict__ offs,
                                                const int* __restrict__ deghist,
                                                int* __restrict__ bucketcur,
                                                int NB, int N) {
    __shared__ int wt[2];
    int t = threadIdx.x;
    int lane = t & 63;
    int w = t >> 6;
    int v = (t < NB) ? blksum[t] : 0;
    int incl = v;
#pragma unroll
    for (int d = 1; d < 64; d <<= 1) {
        int s = __shfl_up(incl, (unsigned)d, 64);
        if (lane >= d) incl += s;
    }
    if (lane == 63) wt[w] = incl;
    __syncthreads();
    int excl = incl - v + (w == 1 ? wt[0] : 0);
    if (t < NB) blkoff[t] = excl;
    if (t == 127) offs[N] = wt[0] + wt[1];
    if (w == 0) {
        int hv = deghist[lane];
        int hincl = hv;
#pragma unroll
        for (int d = 1; d < 64; d <<= 1) {
            int s = __shfl_up(hincl, (unsigned)d, 64);
            if (lane >= d) hincl += s;
        }
        bucketcur[lane] = hincl - hv;
    }
}

// ---------------- phase C: add block offsets, emit degree-sorted meta ------
// meta[pos] = (beg, end, node, dinv^2 bits): one 16B load gives k_prop its
// whole prologue (no dependent perm->begend->dinv chain).
__global__ __launch_bounds__(1024) void k_scan_c(int* __restrict__ offs,
                                                 const int* __restrict__ blkoff,
                                                 const int* __restrict__ deg,
                                                 const float* __restrict__ dinv,
                                                 int* __restrict__ bucketcur,
                                                 uint4* __restrict__ meta, int N) {
    __shared__ int lcnt[64];
    __shared__ int lbase[64];
    int tid = threadIdx.x;
    int i = blockIdx.x * 1024 + tid;
    if (tid < 64) lcnt[tid] = 0;
    __syncthreads();
    int v = 0, d = 0, b = 0, lpos = 0;
    if (i < N) {
        v = offs[i] + blkoff[blockIdx.x];
        offs[i] = v;
        d = deg[i];
        b = d < 63 ? d : 63;
        lpos = atomicAdd(&lcnt[b], 1);
    }
    __syncthreads();
    if (tid < 64) lbase[tid] = (lcnt[tid] != 0) ? atomicAdd(&bucketcur[tid], lcnt[tid]) : 0;
    __syncthreads();
    if (i < N) {
        int pos = lbase[b] + lpos;
        float dv = dinv[i];
        meta[pos] = make_uint4((unsigned)v, (unsigned)(v + d), (unsigned)i,
                               __float_as_uint(dv * dv));
    }
}

// ---------------- CSR fill, atomic-free (rank precomputed in k_deg) --------
__global__ void k_fill(const int* __restrict__ src, const int* __restrict__ dst,
                       const unsigned short* __restrict__ rank,
                       const float* __restrict__ dinv, const int* __restrict__ offs,
                       uint2* __restrict__ csr, int E) {
    int e = blockIdx.x * blockDim.x + threadIdx.x;
    if (e < E) {
        int s = src[e], d = dst[e];
        int pos = offs[d] + (int)rank[e];
        uint2 v;
        v.x = (unsigned)s;
        v.y = __float_as_uint(dinv[s] * dinv[d]);
        csr[pos] = v;
    }
}

// ---------------- h0b = bf16(x @ W^T + b) via 32x32x16 bf16 MFMA -----------
__global__ __launch_bounds__(256) void k_gemm(const float* __restrict__ x,
                                              const float* __restrict__ W,
                                              const float* __restrict__ b,
                                              unsigned short* __restrict__ hb, int N) {
    __shared__ unsigned short Wb[HIDDEN_C * HIDDEN_C];  // 32 KiB bf16
    int tid = threadIdx.x;
#pragma unroll
    for (int i = 0; i < 8; ++i) {
        int c = tid + 256 * i;      // 0..2047
        int m = c >> 4;             // W row (output o)
        int g = c & 15;             // 8-element group within row
        const float4* wsrc = (const float4*)W + m * 32 + g * 2;
        float4 wa = wsrc[0];
        float4 wb = wsrc[1];
        unsigned short t8[8];
        t8[0] = f2bf(wa.x); t8[1] = f2bf(wa.y); t8[2] = f2bf(wa.z); t8[3] = f2bf(wa.w);
        t8[4] = f2bf(wb.x); t8[5] = f2bf(wb.y); t8[6] = f2bf(wb.z); t8[7] = f2bf(wb.w);
        int gs = g ^ (m & 15);
        *(uint4*)&Wb[m * 128 + gs * 8] = *(const uint4*)t8;
    }
    __syncthreads();

    int lane = tid & 63;
    int wv = tid >> 6;
    int row0 = blockIdx.x * 128 + wv * 32;
    int m = lane & 31;
    int half = lane >> 5;

    int row = row0 + m;
    if (row >= N) row = N - 1;
    const float4* xrow = (const float4*)(x + (size_t)row * 128);

    f32x16 acc[4];
#pragma unroll
    for (int t = 0; t < 4; ++t)
#pragma unroll
        for (int r = 0; r < 16; ++r) acc[t][r] = 0.f;

    for (int s = 0; s < 8; ++s) {
        int kb = s * 16 + half * 8;
        float4 x0 = xrow[kb >> 2];
        float4 x1 = xrow[(kb >> 2) + 1];
        union { unsigned short u[8]; short8 v; } af;
        af.u[0] = f2bf(x0.x); af.u[1] = f2bf(x0.y); af.u[2] = f2bf(x0.z); af.u[3] = f2bf(x0.w);
        af.u[4] = f2bf(x1.x); af.u[5] = f2bf(x1.y); af.u[6] = f2bf(x1.z); af.u[7] = f2bf(x1.w);
        int g = kb >> 3;
#pragma unroll
        for (int t = 0; t < 4; ++t) {
            int r = t * 32 + m;
            short8 bfrag = *(const short8*)&Wb[r * 128 + ((g ^ (r & 15)) << 3)];
            acc[t] = __builtin_amdgcn_mfma_f32_32x32x16_bf16(af.v, bfrag, acc[t], 0, 0, 0);
        }
    }

    float bias[4];
#pragma unroll
    for (int t = 0; t < 4; ++t) bias[t] = b[t * 32 + m];
#pragma unroll
    for (int t = 0; t < 4; ++t) {
#pragma unroll
        for (int r = 0; r < 16; ++r) {
            int rrow = (r & 3) + 8 * (r >> 2) + 4 * half;
            int node = row0 + rrow;
            if (node < N) {
                float v = acc[t][r] + bias[t];
                hb[(size_t)node * 128 + t * 32 + m] = f2bf(v);
            }
        }
    }
}

// ---- one APPNP hop: hout = 0.9*(A_hat hin) + 0.1*h0  (all-bf16 state) -----
// v5 (best measured, 499 us total): wave = 4 degree-balanced nodes
// (slot q=L>>4, chunk f=L&15). 4-wide edge loop (clamped indices, zeroed
// weights -> no guard branches) x unroll 2 => up to 8 csr loads + 8 row
// gathers in flight per wave. meta[slot] = (beg, end, node, dinv^2).
__global__ __launch_bounds__(256) void k_prop(const uint4* __restrict__ hin4,
                                              const uint4* __restrict__ h04,
                                              uint4* __restrict__ hout_b,
                                              float* __restrict__ hout_f,
                                              const uint4* __restrict__ meta,
                                              const uint2* __restrict__ csr,
                                              int N, int final_hop) {
    int tid = threadIdx.x;
    int lane = tid & 63;
    int wid = tid >> 6;
    int q = lane >> 4;   // node slot within wave
    int f = lane & 15;   // 16B chunk within row

    int slot = (blockIdx.x * 4 + wid) * 4 + q;
    bool valid = slot < N;

    int node = 0, beg = 0, end = 0;
    float ws = 0.f;
    if (valid) {
        uint4 m = meta[slot];
        beg = (int)m.x;
        end = (int)m.y;
        node = (int)m.z;
        ws = __uint_as_float(m.w);
    }

    // Hoisted per-node loads: h0 row + self row overlap the whole edge loop.
    uint4 hq = make_uint4(0u, 0u, 0u, 0u);
    uint4 ps = make_uint4(0u, 0u, 0u, 0u);
    if (valid) {
        hq = h04[(size_t)node * 16 + f];
        ps = hin4[(size_t)node * 16 + f];
    }

    float acc[8];
#pragma unroll
    for (int i = 0; i < 8; ++i) acc[i] = 0.f;

#pragma unroll 2
    for (int j = beg; j < end; j += 4) {
        int j1 = (j + 1 < end) ? j + 1 : j;
        int j2 = (j + 2 < end) ? j + 2 : j;
        int j3 = (j + 3 < end) ? j + 3 : j;
        uint2 e0 = csr[j];
        uint2 e1 = csr[j1];
        uint2 e2 = csr[j2];
        uint2 e3 = csr[j3];
        uint4 p0 = hin4[(size_t)e0.x * 16 + f];
        uint4 p1 = hin4[(size_t)e1.x * 16 + f];
        uint4 p2 = hin4[(size_t)e2.x * 16 + f];
        uint4 p3 = hin4[(size_t)e3.x * 16 + f];
        float w0 = __uint_as_float(e0.y);
        float w1 = (j + 1 < end) ? __uint_as_float(e1.y) : 0.f;
        float w2 = (j + 2 < end) ? __uint_as_float(e2.y) : 0.f;
        float w3 = (j + 3 < end) ? __uint_as_float(e3.y) : 0.f;
        acc[0] += w0 * bf_lo(p0.x); acc[1] += w0 * bf_hi(p0.x);
        acc[2] += w0 * bf_lo(p0.y); acc[3] += w0 * bf_hi(p0.y);
        acc[4] += w0 * bf_lo(p0.z); acc[5] += w0 * bf_hi(p0.z);
        acc[6] += w0 * bf_lo(p0.w); acc[7] += w0 * bf_hi(p0.w);
        acc[0] += w1 * bf_lo(p1.x); acc[1] += w1 * bf_hi(p1.x);
        acc[2] += w1 * bf_lo(p1.y); acc[3] += w1 * bf_hi(p1.y);
        acc[4] += w1 * bf_lo(p1.z); acc[5] += w1 * bf_hi(p1.z);
        acc[6] += w1 * bf_lo(p1.w); acc[7] += w1 * bf_hi(p1.w);
        acc[0] += w2 * bf_lo(p2.x); acc[1] += w2 * bf_hi(p2.x);
        acc[2] += w2 * bf_lo(p2.y); acc[3] += w2 * bf_hi(p2.y);
        acc[4] += w2 * bf_lo(p2.z); acc[5] += w2 * bf_hi(p2.z);
        acc[6] += w2 * bf_lo(p2.w); acc[7] += w2 * bf_hi(p2.w);
        acc[0] += w3 * bf_lo(p3.x); acc[1] += w3 * bf_hi(p3.x);
        acc[2] += w3 * bf_lo(p3.y); acc[3] += w3 * bf_hi(p3.y);
        acc[4] += w3 * bf_lo(p3.z); acc[5] += w3 * bf_hi(p3.z);
        acc[6] += w3 * bf_lo(p3.w); acc[7] += w3 * bf_hi(p3.w);
    }

    // self-loop (ws==0 only for invalid tail slots)
    acc[0] += ws * bf_lo(ps.x); acc[1] += ws * bf_hi(ps.x);
    acc[2] += ws * bf_lo(ps.y); acc[3] += ws * bf_hi(ps.y);
    acc[4] += ws * bf_lo(ps.z); acc[5] += ws * bf_hi(ps.z);
    acc[6] += ws * bf_lo(ps.w); acc[7] += ws * bf_hi(ps.w);

    if (valid) {
        float o[8];
        o[0] = 0.9f * acc[0] + 0.1f * bf_lo(hq.x);
        o[1] = 0.9f * acc[1] + 0.1f * bf_hi(hq.x);
        o[2] = 0.9f * acc[2] + 0.1f * bf_lo(hq.y);
        o[3] = 0.9f * acc[3] + 0.1f * bf_hi(hq.y);
        o[4] = 0.9f * acc[4] + 0.1f * bf_lo(hq.z);
        o[5] = 0.9f * acc[5] + 0.1f * bf_hi(hq.z);
        o[6] = 0.9f * acc[6] + 0.1f * bf_lo(hq.w);
        o[7] = 0.9f * acc[7] + 0.1f * bf_hi(hq.w);
        if (final_hop) {
            float4* dst0 = (float4*)(hout_f + (size_t)node * 128 + f * 8);
            float4 v0; v0.x = o[0]; v0.y = o[1]; v0.z = o[2]; v0.w = o[3];
            float4 v1; v1.x = o[4]; v1.y = o[5]; v1.z = o[6]; v1.w = o[7];
            dst0[0] = v0;
            dst0[1] = v1;
        } else {
            uint4 p;
            p.x = (unsigned)f2bf(o[0]) | ((unsigned)f2bf(o[1]) << 16);
            p.y = (unsigned)f2bf(o[2]) | ((unsigned)f2bf(o[3]) << 16);
            p.z = (unsigned)f2bf(o[4]) | ((unsigned)f2bf(o[5]) << 16);
            p.w = (unsigned)f2bf(o[6]) | ((unsigned)f2bf(o[7]) << 16);
            hout_b[(size_t)node * 16 + f] = p;
        }
    }
}

extern "C" void kernel_launch(void* const* d_in, const int* in_sizes, int n_in,
                              void* d_out, int out_size, void* d_ws, size_t ws_size,
                              hipStream_t stream) {
    const float* x = (const float*)d_in[0];
    const int* edge = (const int*)d_in[1];  // [2, E]: [0]=src, [1]=dst
    const float* W = (const float*)d_in[2];
    const float* b = (const float*)d_in[3];
    float* out = (float*)d_out;

    const int N = N_NODES_C;
    const int E = N_EDGES_C;
    const int* src = edge;
    const int* dst = edge + E;

    char* ws = (char*)d_ws;
    size_t off = 0;
    auto carve = [&](size_t bytes) -> void* {
        void* p = ws + off;
        off = (off + bytes + 511) & ~(size_t)511;
        return p;
    };
    unsigned short* h0b = (unsigned short*)carve((size_t)N * HIDDEN_C * 2);  // 25.6 MB
    unsigned short* bA  = (unsigned short*)carve((size_t)N * HIDDEN_C * 2);  // 25.6 MB
    unsigned short* bB  = (unsigned short*)carve((size_t)N * HIDDEN_C * 2);  // 25.6 MB
    int*   deg     = (int*)  carve(((size_t)N + 64) * sizeof(int));  // deg + deghist
    int*   deghist = deg + N;
    float* dinv    = (float*)carve((size_t)N * sizeof(float));
    int*   offs    = (int*)  carve((size_t)(N + 1) * sizeof(int));
    unsigned short* rank = (unsigned short*)carve((size_t)E * sizeof(unsigned short));
    uint2* csr     = (uint2*)carve((size_t)E * sizeof(uint2));
    int*   blksum  = (int*)  carve((size_t)SCAN_B * sizeof(int));
    int*   blkoff  = (int*)  carve((size_t)SCAN_B * sizeof(int));
    int*   bucketcur = (int*)carve(64 * sizeof(int));
    uint4* meta    = (uint4*)carve((size_t)N * sizeof(uint4));
    (void)ws_size;

    hipMemsetAsync(deg, 0, ((size_t)N + 64) * sizeof(int), stream);

    int eb = (E + 255) / 256;
    k_deg<<<eb, 256, 0, stream>>>(dst, deg, rank, E);
    k_scan_a<<<SCAN_B, 1024, 0, stream>>>(deg, offs, blksum, dinv, deghist, N);
    k_scan_b<<<1, 128, 0, stream>>>(blksum, blkoff, offs, deghist, bucketcur, SCAN_B, N);
    k_scan_c<<<SCAN_B, 1024, 0, stream>>>(offs, blkoff, deg, dinv, bucketcur, meta, N);
    k_fill<<<eb, 256, 0, stream>>>(src, dst, rank, dinv, offs, csr, E);

    k_gemm<<<(N + 127) / 128, 256, 0, stream>>>(x, W, b, h0b, N);

    // 10 hops: hops 1..9 write bf16 ping-pong, hop 10 writes fp32 d_out
    const uint4* hin = (const uint4*)h0b;
    for (int k = 0; k < K_HOPS_C; ++k) {
        int fin = (k == K_HOPS_C - 1);
        uint4* houtb = ((k & 1) == 0) ? (uint4*)bA : (uint4*)bB;
        k_prop<<<(N + 15) / 16, 256, 0, stream>>>(hin, (const uint4*)h0b,
                                                  fin ? nullptr : houtb,
                                                  fin ? out : nullptr,
                                                  meta, csr, N, fin);
        hin = houtb;
    }
}